// Round 21
// baseline (335.508 us; speedup 1.0000x reference)
//
#include <hip/hip_runtime.h>

typedef float f4 __attribute__((ext_vector_type(4)));
typedef float f32x4 __attribute__((ext_vector_type(4)));
typedef __bf16 bf16x8 __attribute__((ext_vector_type(8)));
typedef __bf16 bf16x4 __attribute__((ext_vector_type(4)));

// out_w fp32 -> bf16 fragment-linear [otile 16][kt 8][m 16][kc 32]
__global__ __launch_bounds__(256) void wcvt(
    const float* __restrict__ wmat, __bf16* __restrict__ wbf)
{
    const int i = (blockIdx.x * 256 + threadIdx.x) * 4;   // o*256+c
    const int o = i >> 8, c = i & 255;
    const f4 v = *(const f4*)&wmat[i];
    bf16x4 ov;
    #pragma unroll
    for (int j = 0; j < 4; ++j) ov[j] = (__bf16)v[j];
    *(bf16x4*)&wbf[((o >> 4) * 8 + (c >> 5)) * 512 + (o & 15) * 32 + (c & 31)] = ov;
}

// R17 attn + in-kernel proj handoff. Block = (b, head, 1x4 strip), 4 waves.
// XCD-aligned: XCD k owns bs in [36k,36k+36) for all 8 heads. After mid
// stores: fence + counter; the LAST of a strip's 8 blocks (no spinning ->
// deadlock-free) runs the strip's proj with mid still hot in its XCD L2.
#define XS(ch_, r_, c_) xs[(ch_) * 169 + (r_) * 21 + (c_)]

__global__ __launch_bounds__(256, 4) void fused(
    const float* __restrict__ x,
    const float* __restrict__ qkv_w,
    const float* __restrict__ qkv_b,
    const float* __restrict__ pos_table,
    const __bf16* __restrict__ wbf,
    __bf16* __restrict__ mid,
    int* __restrict__ ctr,
    float* __restrict__ y)
{
    __shared__ float xs[32 * 169];           // 21.6 KB
    __shared__ __bf16 Ps[4][16][72];         // 9.2 KB
    __shared__ int lastflag;

    const int t = threadIdx.x;

    const int raw = blockIdx.x;               // 2304 = 8 XCD * 288
    const int xcd = raw & 7;
    const int idx = raw >> 3;                 // 0..287
    const int bs  = xcd * 36 + (idx >> 3);    // b*144 + r, XCD-exclusive
    const int head = idx & 7;
    const int b   = bs / 144;
    const int r   = bs % 144;
    const int ni   = r / 6;                   // patch row 0..23
    const int wcol = r % 6;
    const int nj0p = wcol * 4;                // first patch col of strip
    const int c0   = head * 32;

    // ---- stage region: 1280 f4 = 5 per thread, none idle ----
    #pragma unroll
    for (int i = 0; i < 5; ++i) {
        const int idx2 = i * 256 + t;         // (ch, row, cg)
        const int ch  = idx2 / 40;
        const int rem = idx2 % 40;
        const int row = rem / 5, cg = rem % 5;
        const int rg  = min(4 * ni + row, 95);
        const int cg4 = 16 * wcol + 4 * cg;
        const float* xrow = x + (((size_t)b * 256 + c0 + ch) * 96 + rg) * 96;
        f4 v;
        if (cg4 <= 92) {
            v = *(const f4*)&xrow[cg4];
        } else {                              // cols 96..99 clamp to col 95
            const float s = xrow[95];
            v = (f4){s, s, s, s};
        }
        float* xdst = &XS(ch, row, 4 * cg);
        xdst[0] = v.x; xdst[1] = v.y; xdst[2] = v.z; xdst[3] = v.w;
    }

    // per-lane affine coefficients (registers)
    const int wv = t >> 6, l = t & 63;
    const int l16 = l & 15, lg = l >> 4;
    const float qscale = 0.17677669529663687f;

    float kw8[8], kb8[8], qw8[8], qb8[8];
    #pragma unroll
    for (int j = 0; j < 8; ++j) {
        const int c = c0 + 8 * lg + j;
        kw8[j] = qkv_w[256 + c];
        kb8[j] = qkv_b[256 + c];
        qw8[j] = qkv_w[c] * qscale;
        qb8[j] = qkv_b[c] * qscale;
    }
    float vw2[2], vb2[2];
    #pragma unroll
    for (int nt = 0; nt < 2; ++nt) {
        const int c = c0 + nt * 16 + l16;
        vw2[nt] = qkv_w[512 + c];
        vb2[nt] = qkv_b[512 + c];
    }

    __syncthreads();

    const int nj  = nj0p + wv;
    const int cbl = 4 * wv;                  // patch origin col within region

    // ---- Q fragment (row = l16, ch = 8lg+j) ----
    bf16x8 qf;
    {
        const int qrow = l16 >> 2, qcol = cbl + (l16 & 3);
        #pragma unroll
        for (int j = 0; j < 8; ++j)
            qf[j] = (__bf16)(XS(8 * lg + j, qrow, qcol) * qw8[j] + qb8[j]);
    }

    // ---- QK^T: build K fragment per t4 and mfma ----
    const f32x4 zf = {0.f, 0.f, 0.f, 0.f};
    f32x4 sacc[4];
    #pragma unroll
    for (int t4 = 0; t4 < 4; ++t4) {
        const int px = l16 + 16 * t4;
        const int kr = px >> 3, kc = cbl + (px & 7);
        bf16x8 kf;
        #pragma unroll
        for (int j = 0; j < 8; ++j)
            kf[j] = (__bf16)(XS(8 * lg + j, kr, kc) * kw8[j] + kb8[j]);
        sacc[t4] = __builtin_amdgcn_mfma_f32_16x16x32_bf16(qf, kf, zf, 0, 0, 0);
    }

    // ---- bias + row softmax ----
    float sv[4][4], rinv[4];
    #pragma unroll
    for (int rr = 0; rr < 4; ++rr) {
        const int qrow = lg * 4 + rr;
        const int qi = qrow >> 2, qj = qrow & 3;
        float m = -1e30f;
        #pragma unroll
        for (int t4 = 0; t4 < 4; ++t4) {
            const int kcol = l16 + 16 * t4;
            const int ki = kcol >> 3, kj = kcol & 7;
            const float s = sacc[t4][rr]
                + pos_table[((qi - ki + 7) * 15 + (qj - kj + 7)) * 8 + head];
            sv[t4][rr] = s;
            m = fmaxf(m, s);
        }
        #pragma unroll
        for (int off = 8; off >= 1; off >>= 1)
            m = fmaxf(m, __shfl_xor(m, off, 16));
        float sum = 0.f;
        #pragma unroll
        for (int t4 = 0; t4 < 4; ++t4) {
            const float p = __expf(sv[t4][rr] - m);
            sv[t4][rr] = p;
            sum += p;
        }
        #pragma unroll
        for (int off = 8; off >= 1; off >>= 1)
            sum += __shfl_xor(sum, off, 16);
        rinv[rr] = 1.0f / sum;
        #pragma unroll
        for (int t4 = 0; t4 < 4; ++t4)
            Ps[wv][qrow][l16 + 16 * t4] = (__bf16)sv[t4][rr];
    }

    // ---- PV: build V fragments from xs and mfma ----
    f32x4 oa = zf, ob = zf;
    #pragma unroll
    for (int kt = 0; kt < 2; ++kt) {
        bf16x8 pf = *(const bf16x8*)&Ps[wv][l16][lg * 8 + 32 * kt];
        bf16x8 v0, v1;
        #pragma unroll
        for (int j = 0; j < 8; ++j) {
            const int px = kt * 32 + 8 * lg + j;
            const int vr = px >> 3, vc = cbl + (px & 7);
            v0[j] = (__bf16)(XS(l16,      vr, vc) * vw2[0] + vb2[0]);
            v1[j] = (__bf16)(XS(16 + l16, vr, vc) * vw2[1] + vb2[1]);
        }
        oa = __builtin_amdgcn_mfma_f32_16x16x32_bf16(pf, v0, oa, 0, 0, 0);
        ob = __builtin_amdgcn_mfma_f32_16x16x32_bf16(pf, v1, ob, 0, 0, 0);
    }

    // ---- epilogue: store O to fragment-linear mid ----
    const int pbase = ni * 384 + lg * 96 + nj * 4;
    __bf16* mbb = mid + (size_t)b * 9216 * 256;
    #pragma unroll
    for (int rr = 0; rr < 4; ++rr) {
        const int p = pbase + rr;
        __bf16* dst = mbb + ((p >> 4) * 8 + head) * 512 + (p & 15) * 32;
        dst[l16]      = (__bf16)(oa[rr] * rinv[rr]);
        dst[16 + l16] = (__bf16)(ob[rr] * rinv[rr]);
    }

    // ---- handoff: last of the strip's 8 head-blocks runs proj ----
    __threadfence();                          // release mid stores
    __syncthreads();
    if (t == 0)
        lastflag = (atomicAdd(&ctr[bs], 1) == 7);
    __syncthreads();
    if (!lastflag) return;
    __threadfence();                          // acquire siblings' mid

    // proj: wave wv -> ptile (4ni+wv)*6+wcol, all 16 otiles (128 MFMA).
    // mid is L2-hot (same XCD, same kernel); wbf L2-resident (128 KB).
    const int fragoff = l16 * 32 + lg * 8;
    const int pt = (4 * ni + wv) * 6 + wcol;
    const __bf16* midb = mid + ((size_t)b * 9216 + (size_t)pt * 16) * 256;
    bf16x8 bfr[8];
    #pragma unroll
    for (int kt = 0; kt < 8; ++kt)
        bfr[kt] = *(const bf16x8*)&midb[kt * 512 + fragoff];

    const int p = pt * 16 + l16;
    for (int ot = 0; ot < 16; ++ot) {
        f32x4 acc = zf;
        #pragma unroll
        for (int kt = 0; kt < 8; ++kt) {
            const bf16x8 af = *(const bf16x8*)&wbf[(ot * 8 + kt) * 512 + fragoff];
            acc = __builtin_amdgcn_mfma_f32_16x16x32_bf16(af, bfr[kt], acc, 0, 0, 0);
        }
        const int o = ot * 16 + lg * 4;
        float* yb = y + ((size_t)b * 256 + o) * 9216 + p;
        #pragma unroll
        for (int rr = 0; rr < 4; ++rr)
            yb[(size_t)rr * 9216] = acc[rr];
    }
}

extern "C" void kernel_launch(void* const* d_in, const int* in_sizes, int n_in,
                              void* d_out, int out_size, void* d_ws, size_t ws_size,
                              hipStream_t stream) {
    const float* x         = (const float*)d_in[0];
    const float* qkv_w     = (const float*)d_in[1];
    const float* qkv_b     = (const float*)d_in[2];
    const float* out_w     = (const float*)d_in[3];
    const float* pos_table = (const float*)d_in[4];
    float* y    = (float*)d_out;
    __bf16* mid = (__bf16*)d_ws;                              // 9.4 MB
    __bf16* wbf = (__bf16*)((char*)d_ws + (12u << 20));       // 128 KB @ 12MB
    int*    ctr = (int*)((char*)d_ws + (13u << 20));          // 288 ints @ 13MB

    hipMemsetAsync(ctr, 0, 288 * sizeof(int), stream);        // capture-legal
    wcvt<<<dim3(64), dim3(256), 0, stream>>>(out_w, wbf);
    fused<<<dim3(2304), dim3(256), 0, stream>>>(
        x, qkv_w, qkv_b, pos_table, wbf, mid, ctr, y);
}

// Round 22
// 33.101 us; speedup vs baseline: 10.1358x; 10.1358x over previous
//
#include <hip/hip_runtime.h>

typedef float f4 __attribute__((ext_vector_type(4)));
typedef float f32x4 __attribute__((ext_vector_type(4)));
typedef __bf16 bf16x8 __attribute__((ext_vector_type(8)));
typedef __bf16 bf16x4 __attribute__((ext_vector_type(4)));

#define NPSIDE 24

// Block = (b, head, 1x4 patch strip), 256 threads = 4 waves, wave = 1 patch.
// XCD-aligned mapping: XCD k owns (b,strip) pairs bs in [36k, 36k+36) for ALL
// 8 heads; proj uses the same map. (= the 33.27 us K16 config)
#define XS(ch_, r_, c_) xs[(ch_) * 169 + (r_) * 21 + (c_)]

__global__ __launch_bounds__(256, 4) void patch_attn(
    const float* __restrict__ x,
    const float* __restrict__ qkv_w,
    const float* __restrict__ qkv_b,
    const float* __restrict__ pos_table,
    const float* __restrict__ wmat,
    __bf16* __restrict__ mid,
    __bf16* __restrict__ wbf)
{
    __shared__ float xs[32 * 169];           // 21.6 KB
    __shared__ __bf16 Ps[4][16][72];         // 9.2 KB   total 30.8 KB

    const int t = threadIdx.x;

    // side job: out_w fp32 -> bf16 fragment-linear (blocks 0..63, raw id)
    if (blockIdx.x < 64) {
        const int i = (blockIdx.x * 256 + t) * 4;   // o*256+c
        const int o = i >> 8, c = i & 255;
        const f4 v = *(const f4*)&wmat[i];
        bf16x4 ov;
        #pragma unroll
        for (int j = 0; j < 4; ++j) ov[j] = (__bf16)v[j];
        *(bf16x4*)&wbf[((o >> 4) * 8 + (c >> 5)) * 512 + (o & 15) * 32 + (c & 31)] = ov;
    }

    const int raw = blockIdx.x;               // 2304 = 8 XCD * 288
    const int xcd = raw & 7;
    const int idx = raw >> 3;                 // 0..287
    const int bs  = xcd * 36 + (idx >> 3);    // b*144 + r, XCD-exclusive
    const int head = idx & 7;
    const int b   = bs / 144;
    const int r   = bs % 144;
    const int ni   = r / 6;                   // patch row 0..23
    const int nj0p = (r % 6) * 4;             // first patch col of strip
    const int c0   = head * 32;

    // ---- stage region: 1280 f4 = 5 per thread, none idle ----
    #pragma unroll
    for (int i = 0; i < 5; ++i) {
        const int idx2 = i * 256 + t;         // (ch, row, cg)
        const int ch  = idx2 / 40;
        const int rem = idx2 % 40;
        const int row = rem / 5, cg = rem % 5;
        const int rg  = min(4 * ni + row, 95);
        const int cg4 = 16 * (r % 6) + 4 * cg;
        const float* xrow = x + (((size_t)b * 256 + c0 + ch) * 96 + rg) * 96;
        f4 v;
        if (cg4 <= 92) {
            v = *(const f4*)&xrow[cg4];
        } else {                              // cols 96..99 -> clamp to col 95
            const float s = xrow[95];
            v = (f4){s, s, s, s};
        }
        float* xdst = &XS(ch, row, 4 * cg);
        xdst[0] = v.x; xdst[1] = v.y; xdst[2] = v.z; xdst[3] = v.w;
    }

    // per-lane affine coefficients (registers)
    const int wv = t >> 6, l = t & 63;
    const int l16 = l & 15, lg = l >> 4;
    const float qscale = 0.17677669529663687f;

    float kw8[8], kb8[8], qw8[8], qb8[8];
    #pragma unroll
    for (int j = 0; j < 8; ++j) {
        const int c = c0 + 8 * lg + j;
        kw8[j] = qkv_w[256 + c];
        kb8[j] = qkv_b[256 + c];
        qw8[j] = qkv_w[c] * qscale;
        qb8[j] = qkv_b[c] * qscale;
    }
    float vw2[2], vb2[2];
    #pragma unroll
    for (int nt = 0; nt < 2; ++nt) {
        const int c = c0 + nt * 16 + l16;
        vw2[nt] = qkv_w[512 + c];
        vb2[nt] = qkv_b[512 + c];
    }

    __syncthreads();

    const int nj  = nj0p + wv;
    const int cbl = 4 * wv;                  // patch origin col within region

    // ---- Q fragment (row = l16, ch = 8lg+j) ----
    bf16x8 qf;
    {
        const int qrow = l16 >> 2, qcol = cbl + (l16 & 3);
        #pragma unroll
        for (int j = 0; j < 8; ++j)
            qf[j] = (__bf16)(XS(8 * lg + j, qrow, qcol) * qw8[j] + qb8[j]);
    }

    // ---- QK^T: build K fragment per t4 and mfma ----
    const f32x4 zf = {0.f, 0.f, 0.f, 0.f};
    f32x4 sacc[4];
    #pragma unroll
    for (int t4 = 0; t4 < 4; ++t4) {
        const int px = l16 + 16 * t4;
        const int kr = px >> 3, kc = cbl + (px & 7);
        bf16x8 kf;
        #pragma unroll
        for (int j = 0; j < 8; ++j)
            kf[j] = (__bf16)(XS(8 * lg + j, kr, kc) * kw8[j] + kb8[j]);
        sacc[t4] = __builtin_amdgcn_mfma_f32_16x16x32_bf16(qf, kf, zf, 0, 0, 0);
    }

    // ---- bias + row softmax ----
    float sv[4][4], rinv[4];
    #pragma unroll
    for (int rr = 0; rr < 4; ++rr) {
        const int qrow = lg * 4 + rr;
        const int qi = qrow >> 2, qj = qrow & 3;
        float m = -1e30f;
        #pragma unroll
        for (int t4 = 0; t4 < 4; ++t4) {
            const int kcol = l16 + 16 * t4;
            const int ki = kcol >> 3, kj = kcol & 7;
            const float s = sacc[t4][rr]
                + pos_table[((qi - ki + 7) * 15 + (qj - kj + 7)) * 8 + head];
            sv[t4][rr] = s;
            m = fmaxf(m, s);
        }
        #pragma unroll
        for (int off = 8; off >= 1; off >>= 1)
            m = fmaxf(m, __shfl_xor(m, off, 16));
        float sum = 0.f;
        #pragma unroll
        for (int t4 = 0; t4 < 4; ++t4) {
            const float p = __expf(sv[t4][rr] - m);
            sv[t4][rr] = p;
            sum += p;
        }
        #pragma unroll
        for (int off = 8; off >= 1; off >>= 1)
            sum += __shfl_xor(sum, off, 16);
        rinv[rr] = 1.0f / sum;
        #pragma unroll
        for (int t4 = 0; t4 < 4; ++t4)
            Ps[wv][qrow][l16 + 16 * t4] = (__bf16)sv[t4][rr];
    }
    // Ps is wave-private: compiler's lgkmcnt ordering suffices, no barrier.

    // ---- PV: build V fragments from xs and mfma ----
    f32x4 oa = zf, ob = zf;
    #pragma unroll
    for (int kt = 0; kt < 2; ++kt) {
        bf16x8 pf = *(const bf16x8*)&Ps[wv][l16][lg * 8 + 32 * kt];
        bf16x8 v0, v1;
        #pragma unroll
        for (int j = 0; j < 8; ++j) {
            const int px = kt * 32 + 8 * lg + j;
            const int vr = px >> 3, vc = cbl + (px & 7);
            v0[j] = (__bf16)(XS(l16,      vr, vc) * vw2[0] + vb2[0]);
            v1[j] = (__bf16)(XS(16 + l16, vr, vc) * vw2[1] + vb2[1]);
        }
        oa = __builtin_amdgcn_mfma_f32_16x16x32_bf16(pf, v0, oa, 0, 0, 0);
        ob = __builtin_amdgcn_mfma_f32_16x16x32_bf16(pf, v1, ob, 0, 0, 0);
    }

    // ---- epilogue: store O to fragment-linear mid ----
    const int pbase = ni * 384 + lg * 96 + nj * 4;
    __bf16* mbb = mid + (size_t)b * 9216 * 256;
    #pragma unroll
    for (int rr = 0; rr < 4; ++rr) {
        const int p = pbase + rr;
        __bf16* dst = mbb + ((p >> 4) * 8 + head) * 512 + (p & 15) * 32;
        dst[l16]      = (__bf16)(oa[rr] * rinv[rr]);
        dst[16 + l16] = (__bf16)(ob[rr] * rinv[rr]);
    }
}

// y[b,o,p] = sum_c w[o,c]*mid[b,p,c]; fragment-linear operands.
// K16 proj with ONE change: mid fragment loads issued BEFORE w staging so the
// cold (post-kernel-boundary) L3 latency overlaps the 32 KB stage + barrier.
// Stores are plain (NT was the R18 regression).
__global__ __launch_bounds__(256) void proj(
    const __bf16* __restrict__ wbf,   // fragment-linear [16][8][512]
    const __bf16* __restrict__ mid,   // fragment-linear per b [576][8][512]
    float* __restrict__ y)
{
    __shared__ __align__(16) __bf16 wlds[4][8][512];   // 32 KB

    const int t  = threadIdx.x;
    const int wv = t >> 6;
    const int l  = t & 63;
    const int l16 = l & 15, lg = l >> 4;
    const int fragoff = l16 * 32 + lg * 8;

    const int raw = blockIdx.x;               // 0..1151 = 8 XCD * 144
    const int xcd = raw & 7;
    const int seq = raw >> 3;                 // 0..143
    const int pair = seq >> 2;                // 0..35
    const int og4  = seq & 3;
    const int bs = xcd * 36 + pair;           // matches attn's bs on this XCD
    const int b  = bs / 144;
    const int r  = bs % 144;
    const int ni = r / 6, wcol = r % 6;
    const int ot0 = og4 * 4;
    const int pt  = (4 * ni + wv) * 6 + wcol; // wave's ptile

    // ---- mid fragment loads FIRST: cold latency overlaps w staging ----
    const __bf16* midb = mid + ((size_t)b * 9216 + (size_t)pt * 16) * 256;
    bf16x8 bfr[8];
    #pragma unroll
    for (int kt = 0; kt < 8; ++kt)
        bfr[kt] = *(const bf16x8*)&midb[kt * 512 + fragoff];

    // stage 32 KB w slab (4 KB per instruction, fully coalesced)
    {
        const bf16x8* wsrc = (const bf16x8*)&wbf[(size_t)ot0 * 8 * 512];
        bf16x8* wdst = (bf16x8*)&wlds[0][0][0];
        #pragma unroll
        for (int i = 0; i < 8; ++i)
            wdst[t + 256 * i] = wsrc[t + 256 * i];
    }
    __syncthreads();

    f32x4 acc[4];
    #pragma unroll
    for (int ot = 0; ot < 4; ++ot) acc[ot] = (f32x4){0.f, 0.f, 0.f, 0.f};

    #pragma unroll
    for (int ot = 0; ot < 4; ++ot)
        #pragma unroll
        for (int kt = 0; kt < 8; ++kt) {
            const bf16x8 af = *(const bf16x8*)&wlds[ot][kt][fragoff];
            acc[ot] = __builtin_amdgcn_mfma_f32_16x16x32_bf16(af, bfr[kt], acc[ot], 0, 0, 0);
        }

    const int p = pt * 16 + l16;
    #pragma unroll
    for (int ot = 0; ot < 4; ++ot) {
        const int o = (ot0 + ot) * 16 + lg * 4;
        float* yb = y + ((size_t)b * 256 + o) * 9216 + p;
        #pragma unroll
        for (int rr = 0; rr < 4; ++rr)
            yb[(size_t)rr * 9216] = acc[ot][rr];
    }
}

extern "C" void kernel_launch(void* const* d_in, const int* in_sizes, int n_in,
                              void* d_out, int out_size, void* d_ws, size_t ws_size,
                              hipStream_t stream) {
    const float* x         = (const float*)d_in[0];
    const float* qkv_w     = (const float*)d_in[1];
    const float* qkv_b     = (const float*)d_in[2];
    const float* out_w     = (const float*)d_in[3];
    const float* pos_table = (const float*)d_in[4];
    float* y    = (float*)d_out;
    __bf16* mid = (__bf16*)d_ws;                              // 9.4 MB
    __bf16* wbf = (__bf16*)((char*)d_ws + (12u << 20));       // 128 KB @ 12MB

    patch_attn<<<dim3(2304), dim3(256), 0, stream>>>(
        x, qkv_w, qkv_b, pos_table, out_w, mid, wbf);
    proj<<<dim3(1152), dim3(256), 0, stream>>>(
        wbf, mid, y);
}